// Round 1
// baseline (272.202 us; speedup 1.0000x reference)
//
#include <hip/hip_runtime.h>
#include <math.h>

#define SEQ 2048
#define VOCAB 2048
#define BATCH 8

typedef unsigned short u16;
typedef __attribute__((ext_vector_type(4))) float f32x4;
typedef __attribute__((ext_vector_type(8))) short bf16x8;

__device__ __forceinline__ u16 f2bf(float f) {
  unsigned int u = __builtin_bit_cast(unsigned int, f);
  u += 0x7fffu + ((u >> 16) & 1u);
  return (u16)(u >> 16);
}

__device__ __forceinline__ void async16(const void* g, void* l) {
  __builtin_amdgcn_global_load_lds((const __attribute__((address_space(1))) void*)g,
                                   (__attribute__((address_space(3))) void*)l, 16, 0, 0);
}

// ---------------- f32 -> bf16 convert ----------------
__global__ __launch_bounds__(256) void cvt_bf16(const float* __restrict__ src, u16* __restrict__ dst, int n4) {
  int i = blockIdx.x * 256 + threadIdx.x;
  if (i >= n4) return;
  float4 v = ((const float4*)src)[i];
  ushort4 o;
  o.x = f2bf(v.x); o.y = f2bf(v.y); o.z = f2bf(v.z); o.w = f2bf(v.w);
  ((ushort4*)dst)[i] = o;
}

// ---------------- NT GEMM: C[i,j] = sum_k A[i,k]*B[j,k], M=N=K=2048, bf16 in ----------------
template<int OUT_BF16>
__global__ __launch_bounds__(256) void gemm_nt(const u16* __restrict__ A, const u16* __restrict__ B,
                                               void* __restrict__ Cp) {
  __shared__ __align__(16) u16 As[128 * 32];
  __shared__ __align__(16) u16 Bs[128 * 32];
  const int tid = threadIdx.x;
  const int wid = tid >> 6;
  const int lane = tid & 63;
  const int m0 = blockIdx.y * 128;
  const int n0 = blockIdx.x * 128;
  const int wr = wid >> 1, wc = wid & 1;
  const int frow = lane & 15;
  const int fk = (lane >> 4) * 8;

  f32x4 acc[4][4];
#pragma unroll
  for (int i = 0; i < 4; ++i)
#pragma unroll
    for (int j = 0; j < 4; ++j) acc[i][j] = (f32x4){0.f, 0.f, 0.f, 0.f};

  const int c0 = wid * 2;
  const int skel = (lane & 3) * 8;

  for (int kt = 0; kt < SEQ; kt += 32) {
    __syncthreads();  // previous iter's LDS reads complete
#pragma unroll
    for (int r = 0; r < 2; ++r) {
      const int chunk = c0 + r;
      const int row = chunk * 16 + (lane >> 2);
      async16(A + (size_t)(m0 + row) * SEQ + kt + skel, &As[chunk * 512]);
      async16(B + (size_t)(n0 + row) * SEQ + kt + skel, &Bs[chunk * 512]);
    }
    __syncthreads();  // compiler drains vmcnt(0) before barrier -> staging complete
    bf16x8 af[4], bfv[4];
#pragma unroll
    for (int mi = 0; mi < 4; ++mi) af[mi] = *(const bf16x8*)&As[(wr * 64 + mi * 16 + frow) * 32 + fk];
#pragma unroll
    for (int ni = 0; ni < 4; ++ni) bfv[ni] = *(const bf16x8*)&Bs[(wc * 64 + ni * 16 + frow) * 32 + fk];
#pragma unroll
    for (int mi = 0; mi < 4; ++mi)
#pragma unroll
      for (int ni = 0; ni < 4; ++ni)
        acc[mi][ni] = __builtin_amdgcn_mfma_f32_16x16x32_bf16(af[mi], bfv[ni], acc[mi][ni], 0, 0, 0);
  }

  const int rbase = m0 + wr * 64;
  const int cbase = n0 + wc * 64;
  const int rl = (lane >> 4) * 4;
  const int cl = lane & 15;
#pragma unroll
  for (int mi = 0; mi < 4; ++mi)
#pragma unroll
    for (int ni = 0; ni < 4; ++ni)
#pragma unroll
      for (int i = 0; i < 4; ++i) {
        int rr = rbase + mi * 16 + rl + i;
        int cc = cbase + ni * 16 + cl;
        if (OUT_BF16) ((u16*)Cp)[(size_t)rr * SEQ + cc] = f2bf(acc[mi][ni][i]);
        else          ((float*)Cp)[(size_t)rr * SEQ + cc] = acc[mi][ni][i];
      }
}

// ---------------- causal row softmax, in place; row 0 zeroed afterwards ----------------
__global__ __launch_bounds__(256) void softmax_causal(float* __restrict__ S1, const float* __restrict__ b1p) {
  const int s = blockIdx.x;
  const int tid = threadIdx.x, lane = tid & 63, w = tid >> 6;
  float* row = S1 + (size_t)s * SEQ;
  __shared__ float red[8];
  if (s == 0) {
    for (int j = tid; j < SEQ; j += 256) row[j] = 0.f;
    return;
  }
  const float c1 = b1p[0] / sqrtf((float)SEQ);
  float mx = -3.0e38f;
  for (int j = tid; j <= s; j += 256) mx = fmaxf(mx, row[j] * c1);
  for (int o = 32; o > 0; o >>= 1) mx = fmaxf(mx, __shfl_down(mx, o));
  if (lane == 0) red[w] = mx;
  __syncthreads();
  if (tid == 0) { float m = red[0]; for (int i = 1; i < 4; ++i) m = fmaxf(m, red[i]); red[4] = m; }
  __syncthreads();
  const float MX = red[4];
  float sm = 0.f;
  for (int j = tid; j <= s; j += 256) sm += expf(row[j] * c1 - MX);
  for (int o = 32; o > 0; o >>= 1) sm += __shfl_down(sm, o);
  if (lane == 0) red[w] = sm;
  __syncthreads();
  if (tid == 0) { float t = 0.f; for (int i = 0; i < 4; ++i) t += red[i]; red[5] = t; }
  __syncthreads();
  const float inv = 1.0f / red[5];
  for (int j = tid; j <= s; j += 256) row[j] = expf(row[j] * c1 - MX) * inv;
  for (int j = s + 1 + tid; j < SEQ; j += 256) row[j] = 0.f;
}

// ---------------- out[b,vb] += scale * sum_t wts[b?,t] * emb[idx[b,t], vb] ----------------
__global__ __launch_bounds__(256) void gather_wsum(const float* __restrict__ wts, int wstride,
                                                   const int* __restrict__ idx, const float* __restrict__ emb,
                                                   float* __restrict__ outp, const float* __restrict__ scale_ptr) {
  const int b = blockIdx.y;
  const int vb = blockIdx.x * 256 + threadIdx.x;
  const int t0 = blockIdx.z * 256;
  const float* w = wts + (size_t)b * wstride;
  float acc = 0.f;
  for (int t = t0; t < t0 + 256; ++t)
    acc += w[t] * emb[(size_t)idx[b * SEQ + t] * VOCAB + vb];
  float sc = scale_ptr ? scale_ptr[0] : 1.0f;
  atomicAdd(&outp[(size_t)b * VOCAB + vb], sc * acc);
}

// ---------------- out[b,i] = sum_v M[i,v]*x[b,v]  (+ optional emb[idx[b,S-1],i]) ----------------
template<int GATHER_ADD>
__global__ __launch_bounds__(256) void matvec_row(const float* __restrict__ M, const float* __restrict__ x,
                                                  float* __restrict__ outp, const int* __restrict__ idx,
                                                  const float* __restrict__ emb) {
  const int i = blockIdx.x;
  const int tid = threadIdx.x, lane = tid & 63, w = tid >> 6;
  const float* Mi = M + (size_t)i * VOCAB;
  float acc[BATCH];
#pragma unroll
  for (int b = 0; b < BATCH; ++b) acc[b] = 0.f;
  for (int v = tid; v < VOCAB; v += 256) {
    float m = Mi[v];
#pragma unroll
    for (int b = 0; b < BATCH; ++b) acc[b] += m * x[b * VOCAB + v];
  }
#pragma unroll
  for (int b = 0; b < BATCH; ++b)
    for (int o = 32; o > 0; o >>= 1) acc[b] += __shfl_down(acc[b], o);
  __shared__ float red[4][BATCH];
  if (lane == 0)
#pragma unroll
    for (int b = 0; b < BATCH; ++b) red[w][b] = acc[b];
  __syncthreads();
  if (tid < BATCH) {
    float s = red[0][tid] + red[1][tid] + red[2][tid] + red[3][tid];
    if (GATHER_ADD) s += emb[(size_t)idx[tid * SEQ + SEQ - 1] * VOCAB + i];
    outp[tid * VOCAB + i] = s;
  }
}

// ---------------- out[b,v] += sum_w x[b,w]*M[w,v]   (transposed matvec) ----------------
__global__ __launch_bounds__(256) void matvec_col(const float* __restrict__ M, const float* __restrict__ x,
                                                  float* __restrict__ outp) {
  const int vb = blockIdx.x * 256 + threadIdx.x;
  const int w0 = blockIdx.y * 128;
  __shared__ float xs[BATCH][128];
  for (int k = threadIdx.x; k < BATCH * 128; k += 256)
    xs[k >> 7][k & 127] = x[(k >> 7) * VOCAB + w0 + (k & 127)];
  __syncthreads();
  float acc[BATCH];
#pragma unroll
  for (int b = 0; b < BATCH; ++b) acc[b] = 0.f;
  for (int j = 0; j < 128; ++j) {
    float m = M[(size_t)(w0 + j) * VOCAB + vb];
#pragma unroll
    for (int b = 0; b < BATCH; ++b) acc[b] += xs[b][j] * m;
  }
#pragma unroll
  for (int b = 0; b < BATCH; ++b) atomicAdd(&outp[b * VOCAB + vb], acc[b]);
}

// ---------------- e[b,s]=E[b,s].r[b], u[b,s]=E[b,s].w[b] ----------------
__global__ __launch_bounds__(256) void dots_eu(const int* __restrict__ idx, const float* __restrict__ emb,
                                               const float* __restrict__ rv, const float* __restrict__ wv,
                                               float* __restrict__ e, float* __restrict__ u) {
  const int b = blockIdx.y;
  const int s0 = blockIdx.x * 32;
  const int tid = threadIdx.x, lane = tid & 63, wvd = tid >> 6;
  __shared__ __align__(16) float rs[VOCAB];
  __shared__ __align__(16) float ws[VOCAB];
  for (int k = tid; k < VOCAB; k += 256) { rs[k] = rv[b * VOCAB + k]; ws[k] = wv[b * VOCAB + k]; }
  __syncthreads();
  for (int ii = 0; ii < 8; ++ii) {
    const int s = s0 + wvd * 8 + ii;
    const int rw = idx[b * SEQ + s];
    const float4* er = (const float4*)(emb + (size_t)rw * VOCAB);
    const float4* r4 = (const float4*)rs;
    const float4* w4 = (const float4*)ws;
    float ae = 0.f, au = 0.f;
#pragma unroll
    for (int j = 0; j < 8; ++j) {
      int v4 = j * 64 + lane;
      float4 em = er[v4], rr = r4[v4], ww = w4[v4];
      ae += em.x * rr.x + em.y * rr.y + em.z * rr.z + em.w * rr.w;
      au += em.x * ww.x + em.y * ww.y + em.z * ww.z + em.w * ww.w;
    }
    for (int o = 32; o > 0; o >>= 1) { ae += __shfl_down(ae, o); au += __shfl_down(au, o); }
    if (lane == 0) { e[b * SEQ + s] = ae; u[b * SEQ + s] = au; }
  }
}

// ---------------- vv[b,s] = sum_{t<=s} A1[s,t]*u[b,t] ----------------
__global__ __launch_bounds__(256) void a1_apply(const float* __restrict__ A1, const float* __restrict__ u,
                                                float* __restrict__ vv) {
  const int s = blockIdx.x;
  const int tid = threadIdx.x, lane = tid & 63, w = tid >> 6;
  const float* row = A1 + (size_t)s * SEQ;
  float acc[BATCH];
#pragma unroll
  for (int b = 0; b < BATCH; ++b) acc[b] = 0.f;
  for (int t = tid; t <= s; t += 256) {
    float a = row[t];
#pragma unroll
    for (int b = 0; b < BATCH; ++b) acc[b] += a * u[b * SEQ + t];
  }
#pragma unroll
  for (int b = 0; b < BATCH; ++b)
    for (int o = 32; o > 0; o >>= 1) acc[b] += __shfl_down(acc[b], o);
  __shared__ float red[4][BATCH];
  if (lane == 0)
#pragma unroll
    for (int b = 0; b < BATCH; ++b) red[w][b] = acc[b];
  __syncthreads();
  if (tid < BATCH) vv[tid * SEQ + s] = red[0][tid] + red[1][tid] + red[2][tid] + red[3][tid];
}

// ---------------- A2[b,:] = softmax(c2*(e+vv) with last-two masked) ----------------
__global__ __launch_bounds__(256) void softmax2(const float* __restrict__ e, const float* __restrict__ vv,
                                                float* __restrict__ a2, const float* __restrict__ b2p) {
  const int b = blockIdx.x;
  const int tid = threadIdx.x, lane = tid & 63, w = tid >> 6;
  __shared__ float buf[SEQ];
  __shared__ float red[8];
  const float c2 = b2p[0] / sqrtf((float)VOCAB);
  for (int s = tid; s < SEQ; s += 256)
    buf[s] = (s < SEQ - 2) ? c2 * (e[b * SEQ + s] + vv[b * SEQ + s]) : -1.0e30f;
  __syncthreads();
  float mx = -3.0e38f;
  for (int s = tid; s < SEQ; s += 256) mx = fmaxf(mx, buf[s]);
  for (int o = 32; o > 0; o >>= 1) mx = fmaxf(mx, __shfl_down(mx, o));
  if (lane == 0) red[w] = mx;
  __syncthreads();
  if (tid == 0) { float m = red[0]; for (int i = 1; i < 4; ++i) m = fmaxf(m, red[i]); red[4] = m; }
  __syncthreads();
  const float MX = red[4];
  float sm = 0.f;
  for (int s = tid; s < SEQ; s += 256) sm += expf(buf[s] - MX);
  for (int o = 32; o > 0; o >>= 1) sm += __shfl_down(sm, o);
  if (lane == 0) red[w] = sm;
  __syncthreads();
  if (tid == 0) { float t = 0.f; for (int i = 0; i < 4; ++i) t += red[i]; red[5] = t; }
  __syncthreads();
  const float inv = 1.0f / red[5];
  for (int s = tid; s < SEQ; s += 256)
    a2[b * SEQ + s] = (s < SEQ - 2) ? expf(buf[s] - MX) * inv : 0.f;
}

extern "C" void kernel_launch(void* const* d_in, const int* in_sizes, int n_in,
                              void* d_out, int out_size, void* d_ws, size_t ws_size,
                              hipStream_t stream) {
  (void)in_sizes; (void)n_in; (void)out_size; (void)ws_size;
  const int*   idx = (const int*)d_in[0];
  const float* emb = (const float*)d_in[1];
  const float* pos = (const float*)d_in[2];
  const float* WQ1 = (const float*)d_in[3];
  const float* WK1 = (const float*)d_in[4];
  const float* WV1 = (const float*)d_in[5];
  const float* WQ2 = (const float*)d_in[6];
  const float* WK2 = (const float*)d_in[7];
  const float* b1  = (const float*)d_in[8];
  const float* b2  = (const float*)d_in[9];
  const float* bo  = (const float*)d_in[10];
  float* out = (float*)d_out;

  size_t off = 0;
  auto take = [&](size_t n) { void* p = (char*)d_ws + off; off += (n + 255) & ~(size_t)255; return p; };
  u16*   Pbf  = (u16*)take((size_t)SEQ * SEQ * 2);
  u16*   Wq1b = (u16*)take((size_t)SEQ * SEQ * 2);
  u16*   Wk1b = (u16*)take((size_t)SEQ * SEQ * 2);
  u16*   Q1b  = (u16*)take((size_t)SEQ * SEQ * 2);
  u16*   K1b  = (u16*)take((size_t)SEQ * SEQ * 2);
  float* S1   = (float*)take((size_t)SEQ * SEQ * 4);
  float* g    = (float*)take((size_t)BATCH * VOCAB * 4);
  float* zl   = (float*)take((size_t)BATCH * VOCAB * 4);
  float* q2   = (float*)take((size_t)BATCH * VOCAB * 4);
  float* rr   = (float*)take((size_t)BATCH * VOCAB * 4);
  float* wv   = (float*)take((size_t)BATCH * VOCAB * 4);
  float* ee   = (float*)take((size_t)BATCH * SEQ * 4);
  float* uu   = (float*)take((size_t)BATCH * SEQ * 4);
  float* vv   = (float*)take((size_t)BATCH * SEQ * 4);
  float* a2   = (float*)take((size_t)BATCH * SEQ * 4);

  const int n4 = SEQ * SEQ / 4;
  cvt_bf16<<<n4 / 256, 256, 0, stream>>>(pos, Pbf, n4);
  cvt_bf16<<<n4 / 256, 256, 0, stream>>>(WQ1, Wq1b, n4);
  cvt_bf16<<<n4 / 256, 256, 0, stream>>>(WK1, Wk1b, n4);

  dim3 gg(16, 16);
  gemm_nt<1><<<gg, 256, 0, stream>>>(Pbf, Wq1b, Q1b);   // Q1 = P WQ1^T (bf16 out)
  gemm_nt<1><<<gg, 256, 0, stream>>>(Pbf, Wk1b, K1b);   // K1 = P WK1^T (bf16 out)
  gemm_nt<0><<<gg, 256, 0, stream>>>(Q1b, K1b, S1);     // raw Q1 K1^T (f32 out)

  softmax_causal<<<SEQ, 256, 0, stream>>>(S1, b1);      // -> A1 (row 0 zeroed)

  // g[b] = sum_t A1[S-1,t] * E[b,t]
  hipMemsetAsync(g, 0, (size_t)BATCH * VOCAB * 4, stream);
  gather_wsum<<<dim3(VOCAB / 256, BATCH, SEQ / 256), 256, 0, stream>>>(
      S1 + (size_t)(SEQ - 1) * SEQ, 0, idx, emb, g, nullptr);

  // z_last[b] = E[b,S-1] + WV1 g[b];  q2[b] = WQ2 z_last[b]
  matvec_row<1><<<VOCAB, 256, 0, stream>>>(WV1, g, zl, idx, emb);
  matvec_row<0><<<VOCAB, 256, 0, stream>>>(WQ2, zl, q2, nullptr, nullptr);

  // r[b] = WK2^T q2[b];  w[b] = WV1^T r[b]
  hipMemsetAsync(rr, 0, (size_t)BATCH * VOCAB * 4, stream);
  matvec_col<<<dim3(VOCAB / 256, 16), 256, 0, stream>>>(WK2, q2, rr);
  hipMemsetAsync(wv, 0, (size_t)BATCH * VOCAB * 4, stream);
  matvec_col<<<dim3(VOCAB / 256, 16), 256, 0, stream>>>(WV1, rr, wv);

  // e[b,s] = E[b,s].r[b];  u[b,s] = E[b,s].w[b]
  dots_eu<<<dim3(SEQ / 32, BATCH), 256, 0, stream>>>(idx, emb, rr, wv, ee, uu);

  // vv[b,s] = sum_t A1[s,t] u[b,t]
  a1_apply<<<SEQ, 256, 0, stream>>>(S1, uu, vv);

  // A2 = softmax(c2*(e+vv), mask last two)
  softmax2<<<BATCH, 256, 0, stream>>>(ee, vv, a2, b2);

  // out[b] = beta_out * sum_s A2[b,s] E[b,s]
  hipMemsetAsync(out, 0, (size_t)BATCH * VOCAB * 4, stream);
  gather_wsum<<<dim3(VOCAB / 256, BATCH, SEQ / 256), 256, 0, stream>>>(
      a2, SEQ, idx, emb, out, bo);
}

// Round 2
// 229.703 us; speedup vs baseline: 1.1850x; 1.1850x over previous
//
#include <hip/hip_runtime.h>
#include <math.h>

#define SEQ 2048
#define VOCAB 2048
#define BATCH 8

typedef unsigned short u16;
typedef __attribute__((ext_vector_type(4))) float f32x4;
typedef __attribute__((ext_vector_type(8))) short bf16x8;

__device__ __forceinline__ u16 f2bf(float f) {
  unsigned int u = __builtin_bit_cast(unsigned int, f);
  u += 0x7fffu + ((u >> 16) & 1u);
  return (u16)(u >> 16);
}

__device__ __forceinline__ void async16(const void* g, void* l) {
  __builtin_amdgcn_global_load_lds((const __attribute__((address_space(1))) void*)g,
                                   (__attribute__((address_space(3))) void*)l, 16, 0, 0);
}

// ---------------- f32 -> bf16 convert, 3 arrays in one launch ----------------
__global__ __launch_bounds__(256) void cvt_all(const float* __restrict__ pos, const float* __restrict__ WQ1,
                                               const float* __restrict__ WK1, u16* __restrict__ Pbf,
                                               u16* __restrict__ Wqk) {
  const int i = blockIdx.x * 256 + threadIdx.x;  // over SEQ*SEQ/4 float4s
  const int seg = blockIdx.y;
  const float* src = (seg == 0) ? pos : (seg == 1) ? WQ1 : WK1;
  u16* dst = (seg == 0) ? Pbf : (seg == 1) ? Wqk : Wqk + (size_t)SEQ * SEQ;
  float4 v = ((const float4*)src)[i];
  ushort4 o;
  o.x = f2bf(v.x); o.y = f2bf(v.y); o.z = f2bf(v.z); o.w = f2bf(v.w);
  ((ushort4*)dst)[i] = o;
}

// ---------------- fused Q1/K1 GEMM: C[i,j] = sum_k P[i,k]*Wqk[j,k], N=4096 ----------------
__global__ __launch_bounds__(256) void gemm_qk(const u16* __restrict__ A, const u16* __restrict__ Bw,
                                               u16* __restrict__ Q1b, u16* __restrict__ K1b) {
  __shared__ __align__(16) u16 As[128 * 32];
  __shared__ __align__(16) u16 Bs[128 * 32];
  const int tid = threadIdx.x;
  const int wid = tid >> 6;
  const int lane = tid & 63;
  const int m0 = blockIdx.y * 128;
  const int n0 = blockIdx.x * 128;  // 0..4096
  const int wr = wid >> 1, wc = wid & 1;
  const int frow = lane & 15;
  const int fk = (lane >> 4) * 8;

  f32x4 acc[4][4];
#pragma unroll
  for (int i = 0; i < 4; ++i)
#pragma unroll
    for (int j = 0; j < 4; ++j) acc[i][j] = (f32x4){0.f, 0.f, 0.f, 0.f};

  const int c0 = wid * 2;
  const int skel = (lane & 3) * 8;

  for (int kt = 0; kt < SEQ; kt += 32) {
    __syncthreads();
#pragma unroll
    for (int r = 0; r < 2; ++r) {
      const int chunk = c0 + r;
      const int row = chunk * 16 + (lane >> 2);
      async16(A + (size_t)(m0 + row) * SEQ + kt + skel, &As[chunk * 512]);
      async16(Bw + (size_t)(n0 + row) * SEQ + kt + skel, &Bs[chunk * 512]);
    }
    __syncthreads();
    bf16x8 af[4], bfv[4];
#pragma unroll
    for (int mi = 0; mi < 4; ++mi) af[mi] = *(const bf16x8*)&As[(wr * 64 + mi * 16 + frow) * 32 + fk];
#pragma unroll
    for (int ni = 0; ni < 4; ++ni) bfv[ni] = *(const bf16x8*)&Bs[(wc * 64 + ni * 16 + frow) * 32 + fk];
#pragma unroll
    for (int mi = 0; mi < 4; ++mi)
#pragma unroll
      for (int ni = 0; ni < 4; ++ni)
        acc[mi][ni] = __builtin_amdgcn_mfma_f32_16x16x32_bf16(af[mi], bfv[ni], acc[mi][ni], 0, 0, 0);
  }

  u16* outp = (n0 < SEQ) ? Q1b : K1b;
  const int rbase = m0 + wr * 64;
  const int cbase = (n0 < SEQ ? n0 : n0 - SEQ) + wc * 64;
  const int rl = (lane >> 4) * 4;
  const int cl = lane & 15;
#pragma unroll
  for (int mi = 0; mi < 4; ++mi)
#pragma unroll
    for (int ni = 0; ni < 4; ++ni)
#pragma unroll
      for (int i = 0; i < 4; ++i) {
        int rr = rbase + mi * 16 + rl + i;
        int cc = cbase + ni * 16 + cl;
        outp[(size_t)rr * SEQ + cc] = f2bf(acc[mi][ni][i]);
      }
}

// ---------------- S1 = Q1 K1^T, lower-tri 128x128 tiles only, split-K2, atomic f32 combine ----------------
__global__ __launch_bounds__(256) void gemm_s1(const u16* __restrict__ A, const u16* __restrict__ B,
                                               float* __restrict__ S1) {
  __shared__ __align__(16) u16 As[128 * 32];
  __shared__ __align__(16) u16 Bs[128 * 32];
  const int bid = blockIdx.x;          // 272 = 136 tril tiles x 2 K-splits
  const int split = bid & 1;
  const int t = bid >> 1;
  int ti_m = 0;
  while (((ti_m + 1) * (ti_m + 2)) / 2 <= t) ++ti_m;
  const int ti_n = t - (ti_m * (ti_m + 1)) / 2;
  const int m0 = ti_m * 128;
  const int n0 = ti_n * 128;
  const int kt0 = split * (SEQ / 2);

  const int tid = threadIdx.x;
  const int wid = tid >> 6;
  const int lane = tid & 63;
  const int wr = wid >> 1, wc = wid & 1;
  const int frow = lane & 15;
  const int fk = (lane >> 4) * 8;

  f32x4 acc[4][4];
#pragma unroll
  for (int i = 0; i < 4; ++i)
#pragma unroll
    for (int j = 0; j < 4; ++j) acc[i][j] = (f32x4){0.f, 0.f, 0.f, 0.f};

  const int c0 = wid * 2;
  const int skel = (lane & 3) * 8;

  for (int kt = kt0; kt < kt0 + SEQ / 2; kt += 32) {
    __syncthreads();
#pragma unroll
    for (int r = 0; r < 2; ++r) {
      const int chunk = c0 + r;
      const int row = chunk * 16 + (lane >> 2);
      async16(A + (size_t)(m0 + row) * SEQ + kt + skel, &As[chunk * 512]);
      async16(B + (size_t)(n0 + row) * SEQ + kt + skel, &Bs[chunk * 512]);
    }
    __syncthreads();
    bf16x8 af[4], bfv[4];
#pragma unroll
    for (int mi = 0; mi < 4; ++mi) af[mi] = *(const bf16x8*)&As[(wr * 64 + mi * 16 + frow) * 32 + fk];
#pragma unroll
    for (int ni = 0; ni < 4; ++ni) bfv[ni] = *(const bf16x8*)&Bs[(wc * 64 + ni * 16 + frow) * 32 + fk];
#pragma unroll
    for (int mi = 0; mi < 4; ++mi)
#pragma unroll
      for (int ni = 0; ni < 4; ++ni)
        acc[mi][ni] = __builtin_amdgcn_mfma_f32_16x16x32_bf16(af[mi], bfv[ni], acc[mi][ni], 0, 0, 0);
  }

  const int rbase = m0 + wr * 64;
  const int cbase = n0 + wc * 64;
  const int rl = (lane >> 4) * 4;
  const int cl = lane & 15;
#pragma unroll
  for (int mi = 0; mi < 4; ++mi)
#pragma unroll
    for (int ni = 0; ni < 4; ++ni)
#pragma unroll
      for (int i = 0; i < 4; ++i) {
        int rr = rbase + mi * 16 + rl + i;
        int cc = cbase + ni * 16 + cl;
        atomicAdd(&S1[(size_t)rr * SEQ + cc], acc[mi][ni][i]);
      }
}

// ---------------- causal row softmax, in place, tril-only, single pass ----------------
__global__ __launch_bounds__(256) void softmax_causal(float* __restrict__ S1, const float* __restrict__ b1p) {
  const int s = blockIdx.x;
  const int tid = threadIdx.x, lane = tid & 63, w = tid >> 6;
  if (s == 0) {
    if (tid == 0) S1[0] = 0.f;  // only A1[0,0] is ever read in row 0
    return;
  }
  float* row = S1 + (size_t)s * SEQ;
  __shared__ float buf[SEQ];
  __shared__ float red[8];
  const float c1 = b1p[0] / sqrtf((float)SEQ);
  float mx = -3.0e38f;
  for (int j = tid; j <= s; j += 256) {
    float v = row[j] * c1;
    buf[j] = v;
    mx = fmaxf(mx, v);
  }
  for (int o = 32; o > 0; o >>= 1) mx = fmaxf(mx, __shfl_down(mx, o));
  if (lane == 0) red[w] = mx;
  __syncthreads();
  if (tid == 0) { float m = red[0]; for (int i = 1; i < 4; ++i) m = fmaxf(m, red[i]); red[4] = m; }
  __syncthreads();
  const float MX = red[4];
  float sm = 0.f;
  for (int j = tid; j <= s; j += 256) {
    float e = expf(buf[j] - MX);
    buf[j] = e;
    sm += e;
  }
  for (int o = 32; o > 0; o >>= 1) sm += __shfl_down(sm, o);
  if (lane == 0) red[w] = sm;
  __syncthreads();
  if (tid == 0) { float t = 0.f; for (int i = 0; i < 4; ++i) t += red[i]; red[5] = t; }
  __syncthreads();
  const float inv = 1.0f / red[5];
  for (int j = tid; j <= s; j += 256) row[j] = buf[j] * inv;
}

// ---------------- out[b,vb] += scale * sum_t wts[b?,t] * emb[idx[b,t], vb] ----------------
__global__ __launch_bounds__(256) void gather_wsum(const float* __restrict__ wts, int wstride,
                                                   const int* __restrict__ idx, const float* __restrict__ emb,
                                                   float* __restrict__ outp, const float* __restrict__ scale_ptr) {
  const int b = blockIdx.y;
  const int vb = blockIdx.x * 256 + threadIdx.x;
  const int t0 = blockIdx.z * 256;
  const float* w = wts + (size_t)b * wstride;
  float acc = 0.f;
  for (int t = t0; t < t0 + 256; ++t)
    acc += w[t] * emb[(size_t)idx[b * SEQ + t] * VOCAB + vb];
  float sc = scale_ptr ? scale_ptr[0] : 1.0f;
  atomicAdd(&outp[(size_t)b * VOCAB + vb], sc * acc);
}

// ---------------- out[b,i] = sum_v M[i,v]*x[b,v]  (+ optional emb[idx[b,S-1],i]) ----------------
template<int GATHER_ADD>
__global__ __launch_bounds__(256) void matvec_row(const float* __restrict__ M, const float* __restrict__ x,
                                                  float* __restrict__ outp, const int* __restrict__ idx,
                                                  const float* __restrict__ emb) {
  const int i = blockIdx.x;
  const int tid = threadIdx.x, lane = tid & 63, w = tid >> 6;
  const float* Mi = M + (size_t)i * VOCAB;
  float acc[BATCH];
#pragma unroll
  for (int b = 0; b < BATCH; ++b) acc[b] = 0.f;
  for (int v = tid; v < VOCAB; v += 256) {
    float m = Mi[v];
#pragma unroll
    for (int b = 0; b < BATCH; ++b) acc[b] += m * x[b * VOCAB + v];
  }
#pragma unroll
  for (int b = 0; b < BATCH; ++b)
    for (int o = 32; o > 0; o >>= 1) acc[b] += __shfl_down(acc[b], o);
  __shared__ float red[4][BATCH];
  if (lane == 0)
#pragma unroll
    for (int b = 0; b < BATCH; ++b) red[w][b] = acc[b];
  __syncthreads();
  if (tid < BATCH) {
    float s = red[0][tid] + red[1][tid] + red[2][tid] + red[3][tid];
    if (GATHER_ADD) s += emb[(size_t)idx[tid * SEQ + SEQ - 1] * VOCAB + i];
    outp[tid * VOCAB + i] = s;
  }
}

// ---------------- out[b,v] += sum_w x[b,w]*M[w,v]   (transposed matvec) ----------------
__global__ __launch_bounds__(256) void matvec_col(const float* __restrict__ M, const float* __restrict__ x,
                                                  float* __restrict__ outp) {
  const int vb = blockIdx.x * 256 + threadIdx.x;
  const int w0 = blockIdx.y * 128;
  __shared__ float xs[BATCH][128];
  for (int k = threadIdx.x; k < BATCH * 128; k += 256)
    xs[k >> 7][k & 127] = x[(k >> 7) * VOCAB + w0 + (k & 127)];
  __syncthreads();
  float acc[BATCH];
#pragma unroll
  for (int b = 0; b < BATCH; ++b) acc[b] = 0.f;
  for (int j = 0; j < 128; ++j) {
    float m = M[(size_t)(w0 + j) * VOCAB + vb];
#pragma unroll
    for (int b = 0; b < BATCH; ++b) acc[b] += xs[b][j] * m;
  }
#pragma unroll
  for (int b = 0; b < BATCH; ++b) atomicAdd(&outp[b * VOCAB + vb], acc[b]);
}

// ---------------- e[b,s]=E[b,s].r[b], u[b,s]=E[b,s].w[b] ----------------
__global__ __launch_bounds__(256) void dots_eu(const int* __restrict__ idx, const float* __restrict__ emb,
                                               const float* __restrict__ rv, const float* __restrict__ wv,
                                               float* __restrict__ e, float* __restrict__ u) {
  const int b = blockIdx.y;
  const int s0 = blockIdx.x * 32;
  const int tid = threadIdx.x, lane = tid & 63, wvd = tid >> 6;
  __shared__ __align__(16) float rs[VOCAB];
  __shared__ __align__(16) float ws[VOCAB];
  for (int k = tid; k < VOCAB; k += 256) { rs[k] = rv[b * VOCAB + k]; ws[k] = wv[b * VOCAB + k]; }
  __syncthreads();
  for (int ii = 0; ii < 8; ++ii) {
    const int s = s0 + wvd * 8 + ii;
    const int rw = idx[b * SEQ + s];
    const float4* er = (const float4*)(emb + (size_t)rw * VOCAB);
    const float4* r4 = (const float4*)rs;
    const float4* w4 = (const float4*)ws;
    float ae = 0.f, au = 0.f;
#pragma unroll
    for (int j = 0; j < 8; ++j) {
      int v4 = j * 64 + lane;
      float4 em = er[v4], rr = r4[v4], ww = w4[v4];
      ae += em.x * rr.x + em.y * rr.y + em.z * rr.z + em.w * rr.w;
      au += em.x * ww.x + em.y * ww.y + em.z * ww.z + em.w * ww.w;
    }
    for (int o = 32; o > 0; o >>= 1) { ae += __shfl_down(ae, o); au += __shfl_down(au, o); }
    if (lane == 0) { e[b * SEQ + s] = ae; u[b * SEQ + s] = au; }
  }
}

// ---------------- vv[b,s] = sum_{t<=s} A1[s,t]*u[b,t] ----------------
__global__ __launch_bounds__(256) void a1_apply(const float* __restrict__ A1, const float* __restrict__ u,
                                                float* __restrict__ vv) {
  const int s = blockIdx.x;
  const int tid = threadIdx.x, lane = tid & 63, w = tid >> 6;
  const float* row = A1 + (size_t)s * SEQ;
  float acc[BATCH];
#pragma unroll
  for (int b = 0; b < BATCH; ++b) acc[b] = 0.f;
  for (int t = tid; t <= s; t += 256) {
    float a = row[t];
#pragma unroll
    for (int b = 0; b < BATCH; ++b) acc[b] += a * u[b * SEQ + t];
  }
#pragma unroll
  for (int b = 0; b < BATCH; ++b)
    for (int o = 32; o > 0; o >>= 1) acc[b] += __shfl_down(acc[b], o);
  __shared__ float red[4][BATCH];
  if (lane == 0)
#pragma unroll
    for (int b = 0; b < BATCH; ++b) red[w][b] = acc[b];
  __syncthreads();
  if (tid < BATCH) vv[tid * SEQ + s] = red[0][tid] + red[1][tid] + red[2][tid] + red[3][tid];
}

// ---------------- A2[b,:] = softmax(c2*(e+vv) with last-two masked) ----------------
__global__ __launch_bounds__(256) void softmax2(const float* __restrict__ e, const float* __restrict__ vv,
                                                float* __restrict__ a2, const float* __restrict__ b2p) {
  const int b = blockIdx.x;
  const int tid = threadIdx.x, lane = tid & 63, w = tid >> 6;
  __shared__ float buf[SEQ];
  __shared__ float red[8];
  const float c2 = b2p[0] / sqrtf((float)VOCAB);
  for (int s = tid; s < SEQ; s += 256)
    buf[s] = (s < SEQ - 2) ? c2 * (e[b * SEQ + s] + vv[b * SEQ + s]) : -1.0e30f;
  __syncthreads();
  float mx = -3.0e38f;
  for (int s = tid; s < SEQ; s += 256) mx = fmaxf(mx, buf[s]);
  for (int o = 32; o > 0; o >>= 1) mx = fmaxf(mx, __shfl_down(mx, o));
  if (lane == 0) red[w] = mx;
  __syncthreads();
  if (tid == 0) { float m = red[0]; for (int i = 1; i < 4; ++i) m = fmaxf(m, red[i]); red[4] = m; }
  __syncthreads();
  const float MX = red[4];
  float sm = 0.f;
  for (int s = tid; s < SEQ; s += 256) sm += expf(buf[s] - MX);
  for (int o = 32; o > 0; o >>= 1) sm += __shfl_down(sm, o);
  if (lane == 0) red[w] = sm;
  __syncthreads();
  if (tid == 0) { float t = 0.f; for (int i = 0; i < 4; ++i) t += red[i]; red[5] = t; }
  __syncthreads();
  const float inv = 1.0f / red[5];
  for (int s = tid; s < SEQ; s += 256)
    a2[b * SEQ + s] = (s < SEQ - 2) ? expf(buf[s] - MX) * inv : 0.f;
}

extern "C" void kernel_launch(void* const* d_in, const int* in_sizes, int n_in,
                              void* d_out, int out_size, void* d_ws, size_t ws_size,
                              hipStream_t stream) {
  (void)in_sizes; (void)n_in; (void)out_size; (void)ws_size;
  const int*   idx = (const int*)d_in[0];
  const float* emb = (const float*)d_in[1];
  const float* pos = (const float*)d_in[2];
  const float* WQ1 = (const float*)d_in[3];
  const float* WK1 = (const float*)d_in[4];
  const float* WV1 = (const float*)d_in[5];
  const float* WQ2 = (const float*)d_in[6];
  const float* WK2 = (const float*)d_in[7];
  const float* b1  = (const float*)d_in[8];
  const float* b2  = (const float*)d_in[9];
  const float* bo  = (const float*)d_in[10];
  float* out = (float*)d_out;

  size_t off = 0;
  auto take = [&](size_t n) { void* p = (char*)d_ws + off; off += (n + 255) & ~(size_t)255; return p; };
  u16*   Pbf  = (u16*)take((size_t)SEQ * SEQ * 2);
  u16*   Wqk  = (u16*)take((size_t)SEQ * SEQ * 4);  // [WQ1bf ; WK1bf], 4096 x 2048
  u16*   Q1b  = (u16*)take((size_t)SEQ * SEQ * 2);
  u16*   K1b  = (u16*)take((size_t)SEQ * SEQ * 2);
  float* S1   = (float*)take((size_t)SEQ * SEQ * 4);
  float* g    = (float*)take((size_t)BATCH * VOCAB * 4);
  float* zl   = (float*)take((size_t)BATCH * VOCAB * 4);
  float* q2   = (float*)take((size_t)BATCH * VOCAB * 4);
  float* rr   = (float*)take((size_t)BATCH * VOCAB * 4);
  float* wv   = (float*)take((size_t)BATCH * VOCAB * 4);
  float* ee   = (float*)take((size_t)BATCH * SEQ * 4);
  float* uu   = (float*)take((size_t)BATCH * SEQ * 4);
  float* vv   = (float*)take((size_t)BATCH * SEQ * 4);
  float* a2   = (float*)take((size_t)BATCH * SEQ * 4);

  // convert P, WQ1, WK1 to bf16 (WQ1/WK1 concatenated)
  cvt_all<<<dim3(SEQ * SEQ / 4 / 256, 3), 256, 0, stream>>>(pos, WQ1, WK1, Pbf, Wqk);

  // fused Q1|K1 GEMM: 512 blocks -> 2 resident blocks/CU
  gemm_qk<<<dim3(32, 16), 256, 0, stream>>>(Pbf, Wqk, Q1b, K1b);

  // S1 = Q1 K1^T, tril tiles only, split-K2 deterministic atomic combine
  hipMemsetAsync(S1, 0, (size_t)SEQ * SEQ * 4, stream);
  gemm_s1<<<272, 256, 0, stream>>>(Q1b, K1b, S1);

  softmax_causal<<<SEQ, 256, 0, stream>>>(S1, b1);      // -> A1 in place (tril valid)

  // g[b] = sum_t A1[S-1,t] * E[b,t]
  hipMemsetAsync(g, 0, (size_t)BATCH * VOCAB * 4, stream);
  gather_wsum<<<dim3(VOCAB / 256, BATCH, SEQ / 256), 256, 0, stream>>>(
      S1 + (size_t)(SEQ - 1) * SEQ, 0, idx, emb, g, nullptr);

  // z_last[b] = E[b,S-1] + WV1 g[b];  q2[b] = WQ2 z_last[b]
  matvec_row<1><<<VOCAB, 256, 0, stream>>>(WV1, g, zl, idx, emb);
  matvec_row<0><<<VOCAB, 256, 0, stream>>>(WQ2, zl, q2, nullptr, nullptr);

  // r[b] = WK2^T q2[b];  w[b] = WV1^T r[b]
  hipMemsetAsync(rr, 0, (size_t)BATCH * VOCAB * 4, stream);
  matvec_col<<<dim3(VOCAB / 256, 16), 256, 0, stream>>>(WK2, q2, rr);
  hipMemsetAsync(wv, 0, (size_t)BATCH * VOCAB * 4, stream);
  matvec_col<<<dim3(VOCAB / 256, 16), 256, 0, stream>>>(WV1, rr, wv);

  // e[b,s] = E[b,s].r[b];  u[b,s] = E[b,s].w[b]
  dots_eu<<<dim3(SEQ / 32, BATCH), 256, 0, stream>>>(idx, emb, rr, wv, ee, uu);

  // vv[b,s] = sum_t A1[s,t] u[b,t]
  a1_apply<<<SEQ, 256, 0, stream>>>(S1, uu, vv);

  // A2 = softmax(c2*(e+vv), mask last two)
  softmax2<<<BATCH, 256, 0, stream>>>(ee, vv, a2, b2);

  // out[b] = beta_out * sum_s A2[b,s] E[b,s]
  hipMemsetAsync(out, 0, (size_t)BATCH * VOCAB * 4, stream);
  gather_wsum<<<dim3(VOCAB / 256, BATCH, SEQ / 256), 256, 0, stream>>>(
      a2, SEQ, idx, emb, out, bo);
}